// Round 7
// baseline (120.491 us; speedup 1.0000x reference)
//
#include <hip/hip_runtime.h>

// Problem constants: B=4, N=512, M=512, D=128, H=256, DOUT=128
#define BB    4
#define NN    512
#define MM    512
#define DD    128
#define HH    256
#define DOUTC 128

typedef float v2f __attribute__((ext_vector_type(2)));
typedef float v4f __attribute__((ext_vector_type(4)));

// ---------------------------------------------------------------------------
// Kernel 1: precompute (256 blocks x 1024 threads, 16 rows/block)
// Blocks 0..127:   A rows (from Y, W1[0:D])      -> AC rows 0..2047
// Blocks 128..255: C rows (from X, W1[D:2D]+b1)  -> AC rows 2048..4095
// d-SPLIT: thread = (hq=t&63 -> 4 h, dq=(t>>6)&7 -> 16 d, rh=t>>9 -> 8 rows).
// Each W1 element is loaded by exactly ONE thread (no 16x wave redundancy).
// Partials combined via LDS atomics into swizzled Sacc[r][j][hq]
// (lane-stride-1 -> conflict-free; [r][4hq+j] would be 8-way conflicted).
// ---------------------------------------------------------------------------
__global__ __launch_bounds__(1024, 4) void precompute_ac(
    const float* __restrict__ X, const float* __restrict__ Y,
    const float* __restrict__ W1, const float* __restrict__ b1,
    float* __restrict__ AC)
{
    __shared__ __align__(16) float rows[16][DD];   // 8 KB
    __shared__ __align__(16) float Sacc[16][4][64]; // 16 KB, swizzled [r][j][hq]
    const int bid = blockIdx.x;
    const int t   = threadIdx.x;
    const int isC = bid >> 7;
    const int r0  = (bid & 127) * 16;              // global row (b*512+m)
    const float* src = isC ? X : Y;

    if (t < 512)
        reinterpret_cast<v4f*>(&rows[0][0])[t] =
            reinterpret_cast<const v4f*>(src + (size_t)r0 * DD)[t];
    reinterpret_cast<v4f*>(&Sacc[0][0][0])[t] = (v4f){0.f, 0.f, 0.f, 0.f};
    __syncthreads();

    const int hq = t & 63, h0 = hq * 4;
    const int dq = (t >> 6) & 7;
    const int d0 = dq * 16;
    const int rbase = (t >> 9) * 8;
    const float* wp = W1 + (isC ? DD * HH : 0) + h0;

    v4f acc[8];
#pragma unroll
    for (int r = 0; r < 8; ++r) acc[r] = (v4f){0.f, 0.f, 0.f, 0.f};

#pragma unroll
    for (int dd = 0; dd < 16; dd += 4) {
        const v4f w0 = *reinterpret_cast<const v4f*>(&wp[(d0 + dd + 0) * HH]);
        const v4f w1 = *reinterpret_cast<const v4f*>(&wp[(d0 + dd + 1) * HH]);
        const v4f w2 = *reinterpret_cast<const v4f*>(&wp[(d0 + dd + 2) * HH]);
        const v4f w3 = *reinterpret_cast<const v4f*>(&wp[(d0 + dd + 3) * HH]);
#pragma unroll
        for (int r = 0; r < 8; ++r) {
            const v4f rv = *reinterpret_cast<const v4f*>(&rows[rbase + r][d0 + dd]);
            acc[r] += w0 * rv.x;
            acc[r] += w1 * rv.y;
            acc[r] += w2 * rv.z;
            acc[r] += w3 * rv.w;
        }
    }

#pragma unroll
    for (int r = 0; r < 8; ++r) {
        atomicAdd(&Sacc[rbase + r][0][hq], acc[r].x);
        atomicAdd(&Sacc[rbase + r][1][hq], acc[r].y);
        atomicAdd(&Sacc[rbase + r][2][hq], acc[r].z);
        atomicAdd(&Sacc[rbase + r][3][hq], acc[r].w);
    }
    __syncthreads();

    // write out: thread -> (row r=t>>6, h-quad (t&63)*4)
    {
        const int r = t >> 6;
        const int l = t & 63;
        v4f o;
        o.x = Sacc[r][0][l];
        o.y = Sacc[r][1][l];
        o.z = Sacc[r][2][l];
        o.w = Sacc[r][3][l];
        if (isC) o += *reinterpret_cast<const v4f*>(&b1[l * 4]);
        *reinterpret_cast<v4f*>(&AC[((size_t)(isC * 2048 + r0 + r)) * HH + l * 4]) = o;
    }
}

// ---------------------------------------------------------------------------
// Kernel 2: fused abs-sum + W2 epilogue (256 blocks x 1024 threads)
// Block = (b, nt of 8 n-rows). Thread = (hq=t&63 -> 4 h, qm=t>>6 -> 32 m).
// R=8: each thread accumulates ALL 8 rows -> A-traffic 1.07GB/8 = 134 MB.
//   phase A: acc[8] = sum_m |A+C|, sat = sum_m A  (relu(x) = (x+|x|)/2)
//   combine: swizzled LDS atomics (16 qm-partials)
//   phase B: S[r][h] = 0.5*(SAT + 512*C + ABS)
//   phase C: out = S*W2 + 512*b2 (k-quartered, LDS reduce)
// ---------------------------------------------------------------------------
__global__ __launch_bounds__(1024, 4) void fused_main(
    const float* __restrict__ A, const float* __restrict__ C,
    const float* __restrict__ W2, const float* __restrict__ b2,
    float* __restrict__ out)
{
    __shared__ __align__(16) float Sabs[8][4][64];   // 8 KB, swizzled [r][j][hq]
    __shared__ __align__(16) float SATl[4][64];      // 1 KB, swizzled
    __shared__ __align__(16) float S[8][HH];         // 8 KB
    __shared__ __align__(16) v4f red[3 * 256];       // 12 KB
    const int bid = blockIdx.x;
    const int b   = bid >> 6;
    const int n0  = (bid & 63) * 8;
    const int t   = threadIdx.x;

    // zero Sabs + SATl (2304 floats = 576 v4f)
    if (t < 512)      reinterpret_cast<v4f*>(&Sabs[0][0][0])[t] = (v4f){0.f,0.f,0.f,0.f};
    else if (t < 576) reinterpret_cast<v4f*>(&SATl[0][0])[t - 512] = (v4f){0.f,0.f,0.f,0.f};
    __syncthreads();

    const int hq = t & 63, h0 = hq * 4;
    const int qm = t >> 6;                       // 0..15, 32 m each

    const float* Cb = C + ((size_t)(b * NN + n0)) * HH + h0;
    v4f c[8];
#pragma unroll
    for (int j = 0; j < 8; ++j)
        c[j] = *reinterpret_cast<const v4f*>(&Cb[(size_t)j * HH]);

    v4f acc[8], sat = (v4f){0.f, 0.f, 0.f, 0.f};
#pragma unroll
    for (int j = 0; j < 8; ++j) acc[j] = (v4f){0.f, 0.f, 0.f, 0.f};

    const float* Ab = A + ((size_t)(b * MM + qm * 32)) * HH + h0;
#pragma unroll 4
    for (int m = 0; m < 32; ++m) {
        const v4f a = *reinterpret_cast<const v4f*>(&Ab[(size_t)m * HH]);
        sat += a;
#pragma unroll
        for (int j = 0; j < 8; ++j) {
            const v4f s = a + c[j];
            acc[j].x += fabsf(s.x);
            acc[j].y += fabsf(s.y);
            acc[j].z += fabsf(s.z);
            acc[j].w += fabsf(s.w);
        }
    }

    // combine 16 qm-partials: conflict-free swizzled atomics
#pragma unroll
    for (int j = 0; j < 8; ++j) {
        atomicAdd(&Sabs[j][0][hq], acc[j].x);
        atomicAdd(&Sabs[j][1][hq], acc[j].y);
        atomicAdd(&Sabs[j][2][hq], acc[j].z);
        atomicAdd(&Sabs[j][3][hq], acc[j].w);
    }
    atomicAdd(&SATl[0][hq], sat.x);
    atomicAdd(&SATl[1][hq], sat.y);
    atomicAdd(&SATl[2][hq], sat.z);
    atomicAdd(&SATl[3][hq], sat.w);
    __syncthreads();

    // phase B: S[r][h] = 0.5*(SAT[h] + 512*C[bn,h] + ABS[r][h]); thread -> (r, 2 h)
    {
        const int r  = t >> 7;
        const int hh = (t & 127) * 2;
#pragma unroll
        for (int u = 0; u < 2; ++u) {
            const int h = hh + u;
            const float cv = C[((size_t)(b * NN + n0 + r)) * HH + h];
            S[r][h] = 0.5f * (SATl[h & 3][h >> 2] + 512.f * cv + Sabs[r][h & 3][h >> 2]);
        }
    }
    __syncthreads();

    // phase C: out = S*W2 + 512*b2, k split 4 ways
    const int o0 = (t & 31) * 4;
    const int r  = (t >> 5) & 7;
    const int kq = t >> 8;
    const int k0 = kq * 64;
    v4f a4 = (v4f){0.f, 0.f, 0.f, 0.f};
    const float* w2p = W2 + o0;
#pragma unroll 4
    for (int k = k0; k < k0 + 64; k += 4) {
        const v4f sv = *reinterpret_cast<const v4f*>(&S[r][k]);       // broadcast
        const v4f wA = *reinterpret_cast<const v4f*>(&w2p[(k + 0) * DOUTC]);
        const v4f wB = *reinterpret_cast<const v4f*>(&w2p[(k + 1) * DOUTC]);
        const v4f wC = *reinterpret_cast<const v4f*>(&w2p[(k + 2) * DOUTC]);
        const v4f wD = *reinterpret_cast<const v4f*>(&w2p[(k + 3) * DOUTC]);
        a4 += wA * sv.x;
        a4 += wB * sv.y;
        a4 += wC * sv.z;
        a4 += wD * sv.w;
    }
    if (kq) red[(kq - 1) * 256 + (t & 255)] = a4;
    __syncthreads();
    if (kq == 0) {
#pragma unroll
        for (int p = 0; p < 3; ++p) a4 += red[p * 256 + t];
        a4 += 512.f * (*reinterpret_cast<const v4f*>(&b2[o0]));
        *reinterpret_cast<v4f*>(&out[((size_t)(b * NN + n0 + r)) * DOUTC + o0]) = a4;
    }
}

// ---------------------------------------------------------------------------
extern "C" void kernel_launch(void* const* d_in, const int* in_sizes, int n_in,
                              void* d_out, int out_size, void* d_ws, size_t ws_size,
                              hipStream_t stream) {
    const float* X  = (const float*)d_in[0];
    const float* Y  = (const float*)d_in[1];
    const float* W1 = (const float*)d_in[2];
    const float* b1 = (const float*)d_in[3];
    const float* W2 = (const float*)d_in[4];
    const float* b2 = (const float*)d_in[5];
    float* out = (float*)d_out;

    float* AC = (float*)d_ws;        // 4 MB: A rows 0..2047, C rows 2048..4095
    float* A  = AC;
    float* Cm = AC + 2048 * HH;

    hipLaunchKernelGGL(precompute_ac, dim3(256), dim3(1024), 0, stream,
                       X, Y, W1, b1, AC);
    hipLaunchKernelGGL(fused_main, dim3(256), dim3(1024), 0, stream,
                       A, Cm, W2, b2, out);
}

// Round 8
// 53.859 us; speedup vs baseline: 2.2372x; 2.2372x over previous
//
#include <hip/hip_runtime.h>

// Problem constants: B=4, N=512, M=512, D=128, H=256, DOUT=128
#define BB    4
#define NN    512
#define MM    512
#define DD    128
#define HH    256
#define DOUTC 128

typedef float v2f __attribute__((ext_vector_type(2)));
typedef float v4f __attribute__((ext_vector_type(4)));

__device__ __forceinline__ v4f shfl_xor4(v4f v, int m) {
    v4f r;
    r.x = __shfl_xor(v.x, m, 64);
    r.y = __shfl_xor(v.y, m, 64);
    r.z = __shfl_xor(v.z, m, 64);
    r.w = __shfl_xor(v.w, m, 64);
    return r;
}

// ---------------------------------------------------------------------------
// Kernel 1: precompute (256 blocks x 1024 threads, 16 rows/block)
// Blocks 0..127:   A rows (from Y, W1[0:D])      -> AC rows 0..2047
// Blocks 128..255: C rows (from X, W1[D:2D]+b1)  -> AC rows 2048..4095
// Thread = (hq=t&63 -> 4 h, r=t>>6 row). W1 is read via VMEM; the d-loop is
// chunked into 4x32-d slices (32 KB = L1 size) with a barrier between chunks
// so all 16 waves sweep the same W1 slice in lockstep -> L1 hits, not 16x L2.
// NO LDS atomics (round-7 lesson), no d-split partials.
// ---------------------------------------------------------------------------
__global__ __launch_bounds__(1024) void precompute_ac(
    const float* __restrict__ X, const float* __restrict__ Y,
    const float* __restrict__ W1, const float* __restrict__ b1,
    float* __restrict__ AC)
{
    __shared__ __align__(16) float rows16[16][DD];   // 8 KB
    const int bid = blockIdx.x;
    const int t   = threadIdx.x;
    const int isC = bid >> 7;
    const int r0  = (bid & 127) * 16;                // global row (b*512+m)
    const float* src = isC ? X : Y;

    if (t < 512)
        reinterpret_cast<v4f*>(&rows16[0][0])[t] =
            reinterpret_cast<const v4f*>(src + (size_t)r0 * DD)[t];
    __syncthreads();

    const int hq = t & 63, h0 = hq * 4;
    const int r  = t >> 6;                           // wave-uniform row
    const float* wp = W1 + (isC ? DD * HH : 0) + h0;

    v4f acc = (v4f){0.f, 0.f, 0.f, 0.f};
#pragma unroll
    for (int chunk = 0; chunk < 4; ++chunk) {
        const int dbase = chunk * 32;
#pragma unroll 2
        for (int dg = dbase; dg < dbase + 32; dg += 4) {
            const v4f rv = *reinterpret_cast<const v4f*>(&rows16[r][dg]); // bcast
            const v4f w0 = *reinterpret_cast<const v4f*>(&wp[(dg + 0) * HH]);
            const v4f w1 = *reinterpret_cast<const v4f*>(&wp[(dg + 1) * HH]);
            const v4f w2 = *reinterpret_cast<const v4f*>(&wp[(dg + 2) * HH]);
            const v4f w3 = *reinterpret_cast<const v4f*>(&wp[(dg + 3) * HH]);
            acc += w0 * rv.x;
            acc += w1 * rv.y;
            acc += w2 * rv.z;
            acc += w3 * rv.w;
        }
        if (chunk < 3) __syncthreads();   // keep waves in lockstep for L1 reuse
    }

    if (isC) acc += *reinterpret_cast<const v4f*>(&b1[h0]);
    *reinterpret_cast<v4f*>(&AC[((size_t)(isC * 2048 + r0 + r)) * HH + h0]) = acc;
}

// ---------------------------------------------------------------------------
// Kernel 2: fused abs-sum + W2 epilogue (256 blocks x 1024 threads)
// Block = (b, nt of 8 n-rows). Wave w=t>>6: hgroup=w&3 (64 h), qm=w>>2
// (128 m). Lane l=t&63: hq=l&15 -> h0 = hgroup*64+4*hq; msub=l>>4 (m offset).
// R=1: each (m,h) element of A is read by exactly ONE thread per block ->
// A-traffic 512KB/block = 128 MB total (~4 us L2). relu(x)=(x+|x|)/2.
// Combine: msub via 2x shfl_xor (in-register), qm via one LDS write+add.
// NO LDS atomics (round-7: 36 contended ds-RMW/thread -> 71 us).
// ---------------------------------------------------------------------------
__global__ __launch_bounds__(1024) void fused_main(
    const float* __restrict__ A, const float* __restrict__ C,
    const float* __restrict__ W2, const float* __restrict__ b2,
    float* __restrict__ out)
{
    __shared__ __align__(16) v4f scratch[1536];     // 24 KB: qm-partials / red
    __shared__ __align__(16) v4f satp[3][4][16];    // 3 KB
    __shared__ __align__(16) float S[8][HH];        // 8 KB
    const int bid = blockIdx.x;
    const int b   = bid >> 6;
    const int n0  = (bid & 63) * 8;
    const int t   = threadIdx.x;

    // ---- phase A ----
    const int w    = t >> 6;
    const int l    = t & 63;
    const int hg   = w & 3;
    const int qm   = w >> 2;
    const int hq   = l & 15;
    const int msub = l >> 4;
    const int h0   = hg * 64 + hq * 4;

    const float* Cb = C + ((size_t)(b * NN + n0)) * HH + h0;
    v4f c[8];
#pragma unroll
    for (int j = 0; j < 8; ++j)
        c[j] = *reinterpret_cast<const v4f*>(&Cb[(size_t)j * HH]);

    v4f acc[8], sat = (v4f){0.f, 0.f, 0.f, 0.f};
#pragma unroll
    for (int j = 0; j < 8; ++j) acc[j] = (v4f){0.f, 0.f, 0.f, 0.f};

    // m = qm*128 + i*4 + msub, i = 0..31
    const float* Ab = A + ((size_t)(b * MM + qm * 128 + msub)) * HH + h0;
#pragma unroll 4
    for (int i = 0; i < 32; ++i) {
        const v4f a = *reinterpret_cast<const v4f*>(&Ab[(size_t)i * 4 * HH]);
        sat += a;
#pragma unroll
        for (int j = 0; j < 8; ++j) {
            const v4f s = a + c[j];
            acc[j].x += fabsf(s.x);
            acc[j].y += fabsf(s.y);
            acc[j].z += fabsf(s.z);
            acc[j].w += fabsf(s.w);
        }
    }

    // ---- reduce msub (in-register butterfly over lane bits 4,5) ----
#pragma unroll
    for (int mask = 16; mask <= 32; mask <<= 1) {
#pragma unroll
        for (int j = 0; j < 8; ++j) acc[j] += shfl_xor4(acc[j], mask);
        sat += shfl_xor4(sat, mask);
    }

    // ---- reduce qm via LDS (plain writes, no atomics) ----
    // scratch layout: part[p=qm-1][hg][j][lane<16]  (3*4*8*16 v4f = 24 KB)
    if (qm > 0 && l < 16) {
#pragma unroll
        for (int j = 0; j < 8; ++j)
            scratch[(((qm - 1) * 4 + hg) * 8 + j) * 16 + l] = acc[j];
        satp[qm - 1][hg][l] = sat;
    }
    __syncthreads();

    if (qm == 0 && l < 16) {
#pragma unroll
        for (int p = 0; p < 3; ++p) {
#pragma unroll
            for (int j = 0; j < 8; ++j)
                acc[j] += scratch[((p * 4 + hg) * 8 + j) * 16 + l];
            sat += satp[p][hg][l];
        }
        // S[j][h] = 0.5*(sat + 512*C + abs)
#pragma unroll
        for (int j = 0; j < 8; ++j) {
            const v4f sv = 0.5f * (sat + 512.f * c[j] + acc[j]);
            *reinterpret_cast<v4f*>(&S[j][h0]) = sv;
        }
    }
    __syncthreads();

    // ---- phase C: out = S*W2 + 512*b2, k split 4 ways ----
    const int o0 = (t & 31) * 4;
    const int r  = (t >> 5) & 7;
    const int kq = t >> 8;
    const int k0 = kq * 64;
    v4f a4 = (v4f){0.f, 0.f, 0.f, 0.f};
    const float* w2p = W2 + o0;
#pragma unroll 4
    for (int k = k0; k < k0 + 64; k += 4) {
        const v4f sv = *reinterpret_cast<const v4f*>(&S[r][k]);       // broadcast
        const v4f wA = *reinterpret_cast<const v4f*>(&w2p[(k + 0) * DOUTC]);
        const v4f wB = *reinterpret_cast<const v4f*>(&w2p[(k + 1) * DOUTC]);
        const v4f wC = *reinterpret_cast<const v4f*>(&w2p[(k + 2) * DOUTC]);
        const v4f wD = *reinterpret_cast<const v4f*>(&w2p[(k + 3) * DOUTC]);
        a4 += wA * sv.x;
        a4 += wB * sv.y;
        a4 += wC * sv.z;
        a4 += wD * sv.w;
    }
    if (kq) scratch[(kq - 1) * 256 + (t & 255)] = a4;   // reuse 12 KB of scratch
    __syncthreads();
    if (kq == 0) {
#pragma unroll
        for (int p = 0; p < 3; ++p) a4 += scratch[p * 256 + t];
        a4 += 512.f * (*reinterpret_cast<const v4f*>(&b2[o0]));
        *reinterpret_cast<v4f*>(&out[((size_t)(b * NN + n0 + r)) * DOUTC + o0]) = a4;
    }
}

// ---------------------------------------------------------------------------
extern "C" void kernel_launch(void* const* d_in, const int* in_sizes, int n_in,
                              void* d_out, int out_size, void* d_ws, size_t ws_size,
                              hipStream_t stream) {
    const float* X  = (const float*)d_in[0];
    const float* Y  = (const float*)d_in[1];
    const float* W1 = (const float*)d_in[2];
    const float* b1 = (const float*)d_in[3];
    const float* W2 = (const float*)d_in[4];
    const float* b2 = (const float*)d_in[5];
    float* out = (float*)d_out;

    float* AC = (float*)d_ws;        // 4 MB: A rows 0..2047, C rows 2048..4095
    float* A  = AC;
    float* Cm = AC + 2048 * HH;

    hipLaunchKernelGGL(precompute_ac, dim3(256), dim3(1024), 0, stream,
                       X, Y, W1, b1, AC);
    hipLaunchKernelGGL(fused_main, dim3(256), dim3(1024), 0, stream,
                       A, Cm, W2, b2, out);
}